// Round 8
// baseline (1325.253 us; speedup 1.0000x reference)
//
#include <hip/hip_runtime.h>
#include <math.h>

#define S_ 1024
#define B_ 128
#define F_ 202
#define H_ 100
#define K_ 19
#define XROW_ 208   // x row padded, 16B-aligned
#define HP_ 128     // h padded: recur reads 2x56, logit reads 8x16

// ---------------------------------------------------------------------------
// Kernel 1: one 512-thread workgroup per (direction, batch) chain, 8 waves.
// Round-8 change: weights live in 24 INDIVIDUALLY-NAMED float4 variables
// (no arrays, no allocas). Round 7's float4 arrays were still scratch-demoted
// (VGPR_Count=76 << 96-float footprint; L2-scratch BW model: 157KB/WG/step
// -> ~2800 cy/step, measured 2675) because SROA runs before loop unrolling.
// Named scalars are SSA values -> guaranteed VGPRs.
//
// Arithmetic is bitwise-identical to the round-1/7 passing kernels:
//   thread q4=(hf,jp) owns round-1 accumulator chains a_{2jp}, a_{2jp+1} of
//   half hf (same fmaf order, q ascending); shfl_xor(1) -> (a0+a1)+(a2+a3)
//   per half; shfl_xor(2) -> half0+half1; then +bias / +xp as in round 1.
// Staging pipeline, hermetic barrier, logit tree, atomics: round-7 verbatim.
// ---------------------------------------------------------------------------
__global__ __launch_bounds__(512, 2) void rnn_chain_kernel(
    const float* __restrict__ x,
    const float* __restrict__ Wih_f, const float* __restrict__ Whh_f,
    const float* __restrict__ bih_f, const float* __restrict__ bhh_f,
    const float* __restrict__ Wih_b, const float* __restrict__ Whh_b,
    const float* __restrict__ bih_b, const float* __restrict__ bhh_b,
    const float* __restrict__ Wout,
    float* __restrict__ Lbuf)
{
    const int tid = threadIdx.x;
    const int dir = blockIdx.x >> 7;   // 0 = forward, 1 = backward
    const int b   = blockIdx.x & 127;

    const float* Wih = dir ? Wih_b : Wih_f;
    const float* Whh = dir ? Whh_b : Whh_f;
    const float* bih = dir ? bih_b : bih_f;
    const float* bhh = dir ? bhh_b : bhh_f;

    __shared__ __align__(16) float x_buf[4][XROW_];
    __shared__ __align__(16) float h_buf[2][HP_];

    // proj/recur roles: tid < 400
    const int i  = tid >> 2;         // output index 0..99
    const int q4 = tid & 3;
    const int jp = q4 & 1;           // accumulator-pair (a_{2jp}, a_{2jp+1})
    const int hf = q4 >> 1;          // which half of the dot
    // logit role: tid >= 360 (8-group aligned; 152 threads = 19 tags x 8)
    const int lt = tid - 360;
    const int lk = lt >> 3;          // tag k 0..18
    const int ls = lt & 7;

    // ---- weights as NAMED float4 SSA values (never spillable allocas) ----
    float4 wih0={0,0,0,0},wih1={0,0,0,0},wih2={0,0,0,0},wih3={0,0,0,0},
           wih4_={0,0,0,0},wih5={0,0,0,0},wih6={0,0,0,0},wih7={0,0,0,0},
           wih8={0,0,0,0},wih9={0,0,0,0},wih10={0,0,0,0},wih11={0,0,0,0},
           wih12={0,0,0,0};
    float4 whh0={0,0,0,0},whh1={0,0,0,0},whh2={0,0,0,0},whh3={0,0,0,0},
           whh4_={0,0,0,0},whh5={0,0,0,0},whh6={0,0,0,0};
    float4 wlog0={0,0,0,0},wlog1={0,0,0,0},wlog2={0,0,0,0},wlog3={0,0,0,0};
    float bias = 0.f;

    if (tid < 400) {
        const float* Wp = Wih + (size_t)i * F_;
        const int fb = hf * 104 + 2 * jp;
        // named var R packs chains q=2R (-> .x/.y) and q=2R+1 (-> .z/.w)
        #define WIH_INIT(VN, R) { \
            const int f0 = fb + 8*(R); \
            if (f0 <= 200) { const float2 v = *(const float2*)(Wp + f0); VN.x = v.x; VN.y = v.y; } \
            const int f1 = fb + 8*(R) + 4; \
            if (f1 <= 200) { const float2 v = *(const float2*)(Wp + f1); VN.z = v.x; VN.w = v.y; } \
        }
        WIH_INIT(wih0,0)  WIH_INIT(wih1,1)  WIH_INIT(wih2,2)  WIH_INIT(wih3,3)
        WIH_INIT(wih4_,4) WIH_INIT(wih5,5)  WIH_INIT(wih6,6)  WIH_INIT(wih7,7)
        WIH_INIT(wih8,8)  WIH_INIT(wih9,9)  WIH_INIT(wih10,10) WIH_INIT(wih11,11)
        WIH_INIT(wih12,12)
        #undef WIH_INIT

        const float* Hp = Whh + (size_t)i * H_;
        const int jb = hf * 56 + 2 * jp;
        #define WHH_INIT(VN, R) { \
            const int j0 = jb + 8*(R); \
            if (j0 <= 98) { const float2 v = *(const float2*)(Hp + j0); VN.x = v.x; VN.y = v.y; } \
            const int j1 = jb + 8*(R) + 4; \
            if (j1 <= 98) { const float2 v = *(const float2*)(Hp + j1); VN.z = v.x; VN.w = v.y; } \
        }
        WHH_INIT(whh0,0)  WHH_INIT(whh1,1)  WHH_INIT(whh2,2)  WHH_INIT(whh3,3)
        WHH_INIT(whh4_,4) WHH_INIT(whh5,5)  WHH_INIT(whh6,6)
        #undef WHH_INIT

        if (q4 == 0) bias = bih[i] + bhh[i];
    }
    if (tid >= 360) {
        const float* Op = Wout + (size_t)lk * (2 * H_) + dir * H_;
        #define WLOG_INIT(VN, Q) { \
            const int j0 = ls * 16 + 4*(Q); \
            VN.x = (j0 + 0 < H_) ? Op[j0 + 0] : 0.f; \
            VN.y = (j0 + 1 < H_) ? Op[j0 + 1] : 0.f; \
            VN.z = (j0 + 2 < H_) ? Op[j0 + 2] : 0.f; \
            VN.w = (j0 + 3 < H_) ? Op[j0 + 3] : 0.f; \
        }
        WLOG_INIT(wlog0,0) WLOG_INIT(wlog1,1) WLOG_INIT(wlog2,2) WLOG_INIT(wlog3,3)
        #undef WLOG_INIT
    }

    // proj dot: c0/c1 accumulate chains a_{2jp}/a_{2jp+1}, q ascending (round-1 order)
    #define WIH_FMA(VN, R) { \
        const float2 x0 = *(const float2*)(xb + 8*(R)); \
        c0 = fmaf(VN.x, x0.x, c0); c1 = fmaf(VN.y, x0.y, c1); \
        const float2 x1 = *(const float2*)(xb + 8*(R) + 4); \
        c0 = fmaf(VN.z, x1.x, c0); c1 = fmaf(VN.w, x1.y, c1); \
    }
    #define PROJ_ALL \
        WIH_FMA(wih0,0)  WIH_FMA(wih1,1)  WIH_FMA(wih2,2)  WIH_FMA(wih3,3) \
        WIH_FMA(wih4_,4) WIH_FMA(wih5,5)  WIH_FMA(wih6,6)  WIH_FMA(wih7,7) \
        WIH_FMA(wih8,8)  WIH_FMA(wih9,9)  WIH_FMA(wih10,10) WIH_FMA(wih11,11) \
        WIH_FMA(wih12,12)
    #define WHH_FMA(VN, R) { \
        const float2 h0 = *(const float2*)(hb + 8*(R)); \
        c0 = fmaf(VN.x, h0.x, c0); c1 = fmaf(VN.y, h0.y, c1); \
        const float2 h1 = *(const float2*)(hb + 8*(R) + 4); \
        c0 = fmaf(VN.z, h1.x, c0); c1 = fmaf(VN.w, h1.y, c1); \
    }
    #define RECUR_ALL \
        WHH_FMA(whh0,0)  WHH_FMA(whh1,1)  WHH_FMA(whh2,2)  WHH_FMA(whh3,3) \
        WHH_FMA(whh4_,4) WHH_FMA(whh5,5)  WHH_FMA(whh6,6)
    #define WLOG_FMA(VN, Q) { \
        const float4 hv = *(const float4*)(hb2 + 4*(Q)); \
        a0 = fmaf(VN.x, hv.x, a0); a1 = fmaf(VN.y, hv.y, a1); \
        a2 = fmaf(VN.z, hv.z, a2); a3 = fmaf(VN.w, hv.w, a3); \
    }
    #define LOGIT_ALL \
        WLOG_FMA(wlog0,0) WLOG_FMA(wlog1,1) WLOG_FMA(wlog2,2) WLOG_FMA(wlog3,3)

    // zero x pads (never rewritten; staging covers floats < 202) + h init
    for (int q = tid; q < 4 * XROW_; q += 512) (&x_buf[0][0])[q] = 0.f;
    if (tid < 2 * HP_) (&h_buf[0][0])[tid] = 0.f;
    __syncthreads();

    // plain-stage rows 0,1
    {
        const int p0 = dir ? (S_ - 1) : 0;
        const int p1 = dir ? (S_ - 2) : 1;
        const float* r0 = x + ((size_t)p0 * B_ + b) * F_;
        const float* r1 = x + ((size_t)p1 * B_ + b) * F_;
        if (tid < F_) { x_buf[0][tid] = r0[tid]; x_buf[1][tid] = r1[tid]; }
    }
    __syncthreads();

    // wave-7 staging lanes: two float2 elements per lane (e0 always, e1 if <101)
    const int sl = tid - 448;
    const int e0 = sl;          // float2 index 0..63  (floats 0..127)
    const int e1 = sl + 64;     // float2 index 64..100 iff sl < 37 (floats 128..201)
    float2 sA0 = {0.f, 0.f}, sA1 = {0.f, 0.f};   // holds x row t+2 on even iters
    float2 sB0 = {0.f, 0.f}, sB1 = {0.f, 0.f};   // holds x row t+2 on odd iters
    if (tid >= 448) {
        const int pa = dir ? (S_ - 3) : 2;       // row 2
        const int pb = dir ? (S_ - 4) : 3;       // row 3
        const float* ra = x + ((size_t)pa * B_ + b) * F_;
        const float* rb = x + ((size_t)pb * B_ + b) * F_;
        sA0 = *(const float2*)(ra + e0 * 2);
        if (e1 < 101) sA1 = *(const float2*)(ra + e1 * 2);
        sB0 = *(const float2*)(rb + e0 * 2);
        if (e1 < 101) sB1 = *(const float2*)(rb + e1 * 2);
    }

    // xp for step 0 from x_buf[0] (bitwise round-1 tree via 4-thread split)
    float xp_cur = 0.f, xp_nxt = 0.f;
    if (tid < 400) {
        float c0 = 0.f, c1 = 0.f;
        const float* xb = &x_buf[0][hf * 104 + 2 * jp];
        PROJ_ALL
        float acc = c0 + c1;                    // a_{2jp} + a_{2jp+1}
        acc += __shfl_xor(acc, 1);              // (a0+a1) + (a2+a3)   [per half]
        acc += __shfl_xor(acc, 2);              // half0 + half1
        xp_cur = acc + bias;                    // valid on q4==0
    }
    __syncthreads();

    auto STEP = [&](int t, float2& r0, float2& r1) {
        const int rh = t & 1;          // h_buf slot holding h[t-1]
        const int wh = rh ^ 1;         // slot for h[t]
        const int rx = (t + 1) & 3;    // x_buf slot holding x[t+1]

        // (1) wave 7: commit row t+2 (loaded 2 iters ago), issue loads row t+4
        if (tid >= 448) {
            if (t + 2 < S_) {
                const int ws = (t + 2) & 3;      // != rx -> no reader conflict
                *(float2*)&x_buf[ws][e0 * 2] = r0;
                if (e1 < 101) *(float2*)&x_buf[ws][e1 * 2] = r1;
            }
            if (t + 4 < S_) {
                const int p = dir ? (S_ - 5 - t) : (t + 4);
                const float* rr = x + ((size_t)p * B_ + b) * F_;
                r0 = *(const float2*)(rr + e0 * 2);
                if (e1 < 101) r1 = *(const float2*)(rr + e1 * 2);
            }
        }

        // (2) recurrence: rsum = Whh . h[t-1] + xp[t]  (bitwise round-1 tree)
        if (tid < 400) {
            float c0 = 0.f, c1 = 0.f;
            const float* hb = &h_buf[rh][hf * 56 + 2 * jp];
            RECUR_ALL
            float acc = c0 + c1;
            acc += __shfl_xor(acc, 1);
            acc += __shfl_xor(acc, 2);
            if (q4 == 0) {
                const float v = acc + xp_cur;
                h_buf[wh][i] = tanhf(v);
            }
        }

        // (3) logits for h[t-1] (round-1 16-slice tree) -> atomicAdd
        if (t >= 1 && tid >= 360) {
            float a0 = 0.f, a1 = 0.f, a2 = 0.f, a3 = 0.f;
            const float* hb2 = &h_buf[rh][ls * 16];
            LOGIT_ALL
            float acc = (a0 + a1) + (a2 + a3);
            acc += __shfl_xor(acc, 1);
            acc += __shfl_xor(acc, 2);
            acc += __shfl_xor(acc, 4);
            if (ls == 0) {
                const int pl = dir ? (S_ - t) : (t - 1);
                atomicAdd(&Lbuf[((size_t)pl * B_ + b) * K_ + lk], acc);
            }
        }

        // (4) proj for step t+1 (independent of h)
        if (t + 1 < S_ && tid < 400) {
            float c0 = 0.f, c1 = 0.f;
            const float* xb = &x_buf[rx][hf * 104 + 2 * jp];
            PROJ_ALL
            float acc = c0 + c1;
            acc += __shfl_xor(acc, 1);
            acc += __shfl_xor(acc, 2);
            xp_nxt = acc + bias;
        }
        xp_cur = xp_nxt;

        // (5) hermetic barrier: no memory op crosses in either direction;
        //     vmem (staging loads / logit atomics) stays in flight.
        __asm__ volatile("s_waitcnt lgkmcnt(0)" ::: "memory");
        __builtin_amdgcn_s_barrier();
        __asm__ volatile("" ::: "memory");
    };

    for (int t2 = 0; t2 < S_; t2 += 2) {   // unroll-by-2: static reg-set rotation
        STEP(t2,     sA0, sA1);
        STEP(t2 + 1, sB0, sB1);
    }

    // epilogue: logits for h[S-1] (written at STEP(1023) into slot 0)
    if (tid >= 360) {
        float a0 = 0.f, a1 = 0.f, a2 = 0.f, a3 = 0.f;
        const float* hb2 = &h_buf[0][ls * 16];
        LOGIT_ALL
        float acc = (a0 + a1) + (a2 + a3);
        acc += __shfl_xor(acc, 1);
        acc += __shfl_xor(acc, 2);
        acc += __shfl_xor(acc, 4);
        if (ls == 0) {
            const int pl = dir ? 0 : (S_ - 1);
            atomicAdd(&Lbuf[((size_t)pl * B_ + b) * K_ + lk], acc);
        }
    }
}

// ---------------------------------------------------------------------------
// Kernel 2: round-1 Viterbi verbatim (known-passing, absmax 0.0).
// ---------------------------------------------------------------------------
__global__ __launch_bounds__(256) void viterbi_kernel(
    const float* __restrict__ Lbuf,
    const float* __restrict__ b_out,
    const float* __restrict__ start_t,
    const float* __restrict__ end_t,
    const float* __restrict__ trans,
    float* __restrict__ out)
{
    const int w    = threadIdx.x >> 6;
    const int lane = threadIdx.x & 63;
    const int n    = blockIdx.x * 4 + w;

    __shared__ float         score_s[4][20];
    __shared__ unsigned char hist_s[4][B_][20];
    __shared__ unsigned char tags_s[4][B_];

    const int kk = (lane < K_) ? lane : 0;
    float tcol[K_];
    #pragma unroll
    for (int j = 0; j < K_; ++j) tcol[j] = trans[j * K_ + kk];
    const float bko = b_out[kk];
    const float stk = start_t[kk];
    const float enk = end_t[kk];

    const float* Lrow = Lbuf + (size_t)n * B_ * K_;

    // t = 0: score = start + em[0]
    {
        float lg = -1e30f;
        if (lane < K_) lg = Lrow[kk] + bko;
        float m = lg;
        #pragma unroll
        for (int d = 16; d >= 1; d >>= 1) m = fmaxf(m, __shfl_xor(m, d, 32));
        float pp = (lane < K_) ? expf(lg - m) : 0.f;
        float ssum = pp;
        #pragma unroll
        for (int d = 16; d >= 1; d >>= 1) ssum += __shfl_xor(ssum, d, 32);
        if (lane < K_) score_s[w][lane] = stk + pp / ssum;
    }

    for (int t = 1; t < B_; ++t) {
        float lg = -1e30f;
        if (lane < K_) lg = Lrow[t * K_ + kk] + bko;
        float m = lg;
        #pragma unroll
        for (int d = 16; d >= 1; d >>= 1) m = fmaxf(m, __shfl_xor(m, d, 32));
        float pp = (lane < K_) ? expf(lg - m) : 0.f;
        float ssum = pp;
        #pragma unroll
        for (int d = 16; d >= 1; d >>= 1) ssum += __shfl_xor(ssum, d, 32);
        const float e = pp / ssum;

        float best = -1e30f; int am = 0;
        #pragma unroll
        for (int j = 0; j < K_; ++j) {
            const float v = (score_s[w][j] + tcol[j]) + e;   // ref add order
            if (v > best) { best = v; am = j; }
        }
        if (lane < K_) {
            hist_s[w][t][lane] = (unsigned char)am;
            score_s[w][lane]   = best;   // wave-lockstep: reads precede writes
        }
    }

    if (lane < K_) score_s[w][lane] += enk;

    if (lane == 0) {
        float bestv = score_s[w][0]; int bi = 0;
        for (int j = 1; j < K_; ++j) {
            const float v = score_s[w][j];
            if (v > bestv) { bestv = v; bi = j; }
        }
        int tag = bi;
        tags_s[w][B_ - 1] = (unsigned char)tag;
        for (int t = B_ - 2; t >= 0; --t) {
            tag = hist_s[w][t + 1][tag];
            tags_s[w][t] = (unsigned char)tag;
        }
    }
    out[(size_t)n * B_ + lane]      = (float)tags_s[w][lane];
    out[(size_t)n * B_ + 64 + lane] = (float)tags_s[w][64 + lane];
}

extern "C" void kernel_launch(void* const* d_in, const int* in_sizes, int n_in,
                              void* d_out, int out_size, void* d_ws, size_t ws_size,
                              hipStream_t stream)
{
    const float* x       = (const float*)d_in[0];
    const float* Wih_f   = (const float*)d_in[1];
    const float* Whh_f   = (const float*)d_in[2];
    const float* bih_f   = (const float*)d_in[3];
    const float* bhh_f   = (const float*)d_in[4];
    const float* Wih_b   = (const float*)d_in[5];
    const float* Whh_b   = (const float*)d_in[6];
    const float* bih_b   = (const float*)d_in[7];
    const float* bhh_b   = (const float*)d_in[8];
    const float* Wout    = (const float*)d_in[9];
    const float* b_out   = (const float*)d_in[10];
    const float* start_t = (const float*)d_in[11];
    const float* end_t   = (const float*)d_in[12];
    const float* trans   = (const float*)d_in[13];

    float* Lbuf = (float*)d_ws;           // (S,B,K) fp32 = ~9.96 MB (proven fit)
    float* out  = (float*)d_out;          // (S,B) fp32 tags

    hipMemsetAsync(Lbuf, 0, (size_t)S_ * B_ * K_ * sizeof(float), stream);

    rnn_chain_kernel<<<dim3(256), dim3(512), 0, stream>>>(
        x, Wih_f, Whh_f, bih_f, bhh_f, Wih_b, Whh_b, bih_b, bhh_b, Wout, Lbuf);

    viterbi_kernel<<<dim3(256), dim3(256), 0, stream>>>(
        Lbuf, b_out, start_t, end_t, trans, out);
}